// Round 8
// baseline (241.450 us; speedup 1.0000x reference)
//
#include <hip/hip_runtime.h>
#include <math.h>

// NoisyTopKRouter, round 8: 2 blocks/CU + n-split (no K reduction).
//   - BM=32 tokens/block, grid 512 -> 2 blocks/CU, 4 waves/SIMD (launch_bounds 512,4)
//   - 8 waves = 2 m-tiles x 4 n-quarters; each wave: full K, NT=2, acc = 8 VGPR
//   - B staged per 32-K step into 2x24KB LDS dbuf via global_load_lds; Lred aliased
//   - per wave-step: 6 ds_read_b128 + 12 MFMA + ~24 VALU (bf16x3 split, native cvt)
//   - T5 setprio around MFMA cluster
// Outputs (flat f32): gate_weights [N][64], top2 idx as float [N][2], logits [N][64].

typedef float   f32x4   __attribute__((ext_vector_type(4)));
typedef __bf16  bf16x8  __attribute__((ext_vector_type(8)));
typedef unsigned short ushort8 __attribute__((ext_vector_type(8)));

#define EE 64     // experts
#define E2 128    // gate+noise logit columns
#define BM 32     // tokens per block

__device__ __forceinline__ unsigned short bf16_rne(float f) {
    unsigned int u = __float_as_uint(f);
    u += 0x7fffu + ((u >> 16) & 1u);
    return (unsigned short)(u >> 16);
}
__device__ __forceinline__ float bf16_f32(unsigned short h) {
    return __uint_as_float(((unsigned int)h) << 16);
}
__device__ __forceinline__ void split3(float a, unsigned short& h1,
                                       unsigned short& h2, unsigned short& h3) {
    h1 = bf16_rne(a);
    float r  = a - bf16_f32(h1);     // exact
    h2 = bf16_rne(r);
    float r2 = r - bf16_f32(h2);     // exact
    h3 = bf16_rne(r2);
}

__device__ __forceinline__ void gload_lds16(const void* g, void* l) {
    __builtin_amdgcn_global_load_lds(
        (const __attribute__((address_space(1))) void*)g,
        (__attribute__((address_space(3))) void*)l, 16, 0, 0);
}

// ---- pre-kernel: pack W (gate cols 0..63, noise cols 64..127) into B-frag order.
// Fragment (16x16x32 bf16, verified): lane l holds col=l&15, k=(l>>4)*8+j.
// Packed ushort addr: ((ks*24) + nt*3 + term)*512 + lane*8 + j   (ks = k/32)
__global__ __launch_bounds__(256) void pack_b(
    const float* __restrict__ wg, const float* __restrict__ wn,
    unsigned short* __restrict__ bp, int Hdim)
{
    int pair = blockIdx.x * 4 + (threadIdx.x >> 6);   // (ks, nt)
    int l    = threadIdx.x & 63;
    int ks   = pair >> 3;
    int nt   = pair & 7;
    int col  = nt * 16 + (l & 15);
    int k    = ks * 32 + ((l >> 4) * 8);
    const float* wrow = (col < EE) ? (wg + (size_t)col * Hdim)
                                   : (wn + (size_t)(col - EE) * Hdim);
    float4 v0 = *reinterpret_cast<const float4*>(wrow + k);
    float4 v1 = *reinterpret_cast<const float4*>(wrow + k + 4);
    float vals[8] = {v0.x, v0.y, v0.z, v0.w, v1.x, v1.y, v1.z, v1.w};
    ushort8 t1, t2, t3;
    #pragma unroll
    for (int j = 0; j < 8; ++j) {
        unsigned short a, b, c;
        split3(vals[j], a, b, c);
        t1[j] = a; t2[j] = b; t3[j] = c;
    }
    size_t base = ((size_t)(ks * 8 + nt) * 3) * 512 + (size_t)l * 8;
    *reinterpret_cast<ushort8*>(bp + base        ) = t1;
    *reinterpret_cast<ushort8*>(bp + base + 512  ) = t2;
    *reinterpret_cast<ushort8*>(bp + base + 1024 ) = t3;
}

#define MFMA(a, b, c) __builtin_amdgcn_mfma_f32_16x16x32_bf16((a), (b), (c), 0, 0, 0)

union ShMem {
    unsigned short Bst[2][24 * 512];     // 2 x 24KB step buffers
    float Lred[BM][E2 + 5];              // 17KB, aliased into Bst[0] (used after loop)
};

__global__ __launch_bounds__(512, 4) void router_mfma(
    const float* __restrict__ hs,
    const float* __restrict__ noise,
    const unsigned short* __restrict__ bp,
    float* __restrict__ out_gate,
    float* __restrict__ out_idx,
    float* __restrict__ out_logits,
    int Ntok, int Hdim)
{
    __shared__ ShMem sh;                 // 48KB -> 2 blocks/CU

    const int tid  = threadIdx.x;
    const int lane = tid & 63;
    const int w    = tid >> 6;           // wave 0..7
    const int mi   = w & 1;              // m-tile 0..1
    const int nq   = w >> 1;             // n-quarter 0..3 (cols nq*32 .. nq*32+31)
    const int m0   = blockIdx.x * BM;

    const int steps = Hdim >> 5;         // 128 (even)

    f32x4 acc0 = f32x4{0.f, 0.f, 0.f, 0.f};
    f32x4 acc1 = f32x4{0.f, 0.f, 0.f, 0.f};

    // ---- A source: lane l covers row (l&15) of this wave's m-tile, k-octet (l>>4)*8
    const float* pa = hs + (size_t)(m0 + mi * 16 + (lane & 15)) * Hdim
                         + ((lane >> 4) * 8);

    // ---- B stage chunks: 1536 x 16B per step; chunk c = tid + 512*j (j=0..2)
    //      frag f = c>>6 is wave-uniform (f = w + 8j), lane-linear within -> lane*16B.
    const unsigned short* srcB[3];
    unsigned short* dstB[2][3];
    #pragma unroll
    for (int j = 0; j < 3; ++j) {
        int c = tid + 512 * j;
        int f = c >> 6;                  // 0..23  (nt*3+term)
        int l = c & 63;
        srcB[j]    = bp + (size_t)f * 512 + l * 8;
        dstB[0][j] = &sh.Bst[0][f * 512 + l * 8];
        dstB[1][j] = &sh.Bst[1][f * 512 + l * 8];
    }

    #define STAGE(buf)                                                        \
        do {                                                                  \
            _Pragma("unroll")                                                 \
            for (int j = 0; j < 3; ++j) {                                     \
                gload_lds16(srcB[j], dstB[buf][j]);                           \
                srcB[j] += 12288;                                             \
            }                                                                 \
        } while (0)

    #define LOADA(d0, d1)                                                     \
        do {                                                                  \
            d0 = *reinterpret_cast<const float4*>(pa);                        \
            d1 = *reinterpret_cast<const float4*>(pa + 4);                    \
            pa += 32;                                                         \
        } while (0)

    // COMPUTE: split A (native bf16 cvt), read 6 B frags, 12 dense MFMAs (setprio).
    #define COMPUTE(s0, s1, buf)                                              \
        do {                                                                  \
            float vals[8] = {s0.x, s0.y, s0.z, s0.w, s1.x, s1.y, s1.z, s1.w}; \
            bf16x8 A1, A2, A3;                                                \
            _Pragma("unroll")                                                 \
            for (int j = 0; j < 8; ++j) {                                     \
                float a  = vals[j];                                           \
                __bf16 h1 = (__bf16)a;                                        \
                float r  = a - (float)h1;                                     \
                __bf16 h2 = (__bf16)r;                                        \
                float r2 = r - (float)h2;                                     \
                __bf16 h3 = (__bf16)r2;                                       \
                A1[j] = h1; A2[j] = h2; A3[j] = h3;                           \
            }                                                                 \
            const unsigned short* bb = &sh.Bst[buf][lane * 8];                \
            bf16x8 b10 = __builtin_bit_cast(bf16x8, *reinterpret_cast<const ushort8*>(bb + (nq * 6 + 0) * 512)); \
            bf16x8 b20 = __builtin_bit_cast(bf16x8, *reinterpret_cast<const ushort8*>(bb + (nq * 6 + 1) * 512)); \
            bf16x8 b30 = __builtin_bit_cast(bf16x8, *reinterpret_cast<const ushort8*>(bb + (nq * 6 + 2) * 512)); \
            bf16x8 b11 = __builtin_bit_cast(bf16x8, *reinterpret_cast<const ushort8*>(bb + (nq * 6 + 3) * 512)); \
            bf16x8 b21 = __builtin_bit_cast(bf16x8, *reinterpret_cast<const ushort8*>(bb + (nq * 6 + 4) * 512)); \
            bf16x8 b31 = __builtin_bit_cast(bf16x8, *reinterpret_cast<const ushort8*>(bb + (nq * 6 + 5) * 512)); \
            __builtin_amdgcn_s_setprio(1);                                    \
            acc0 = MFMA(A1, b10, acc0);                                       \
            acc0 = MFMA(A1, b20, acc0);                                       \
            acc0 = MFMA(A2, b10, acc0);                                       \
            acc0 = MFMA(A2, b20, acc0);                                       \
            acc0 = MFMA(A1, b30, acc0);                                       \
            acc0 = MFMA(A3, b10, acc0);                                       \
            acc1 = MFMA(A1, b11, acc1);                                       \
            acc1 = MFMA(A1, b21, acc1);                                       \
            acc1 = MFMA(A2, b11, acc1);                                       \
            acc1 = MFMA(A2, b21, acc1);                                       \
            acc1 = MFMA(A1, b31, acc1);                                       \
            acc1 = MFMA(A3, b11, acc1);                                       \
            __builtin_amdgcn_s_setprio(0);                                    \
        } while (0)

    // ---- prologue: stage step 0, load A step 0 ----
    STAGE(0);
    float4 c0, c1, n0, n1;
    LOADA(c0, c1);
    __syncthreads();                       // vmcnt(0) drain -> buf0 ready

    // ---- main loop: one barrier per step; stage issued a full step ahead ----
    for (int s = 0; s < steps; s += 2) {
        STAGE(1);                          // step s+1
        LOADA(n0, n1);                     // A step s+1
        COMPUTE(c0, c1, 0);                // step s
        __syncthreads();
        if (s + 2 < steps) {
            STAGE(0);                      // step s+2
            LOADA(c0, c1);
        }
        COMPUTE(n0, n1, 1);                // step s+1
        __syncthreads();
    }

    // ---- write logits tile (disjoint columns per wave; no reduction needed) ----
    // C/D frag (verified): reg r -> row=(lane>>4)*4+r, col=lane&15.
    {
        int row = mi * 16 + (lane >> 4) * 4;
        int col = nq * 32 + (lane & 15);
        #pragma unroll
        for (int r = 0; r < 4; ++r) {
            sh.Lred[row + r][col]      = acc0[r];
            sh.Lred[row + r][col + 16] = acc1[r];
        }
    }
    __syncthreads();

    // ---- per-token epilogue (proven path): one thread per token ----
    if (tid < BM) {
        const int t   = tid;
        const int tok = m0 + t;
        const float* nrow = noise + (size_t)tok * EE;
        float* lrow = out_logits + (size_t)tok * EE;

        float m = -3.4e38f;
        for (int e = 0; e < EE; ++e) {
            float gv = sh.Lred[t][e];
            float nv = sh.Lred[t][EE + e];
            float sp = fmaxf(nv, 0.f) + log1pf(expf(-fabsf(nv)));  // stable softplus
            float l  = fmaf(nrow[e], sp, gv);                      // NOISE_STD = 1
            lrow[e]  = l;
            sh.Lred[t][e] = l;
            m = fmaxf(m, l);
        }

        float Z = 0.f;
        float p1 = -1.f, p2 = -1.f;
        int   i1 = 0,    i2 = 0;
        for (int e = 0; e < EE; ++e) {
            float p = expf(sh.Lred[t][e] - m);
            Z += p;
            if (p > p1)      { p2 = p1; i2 = i1; p1 = p; i1 = e; }  // ties -> lower idx
            else if (p > p2) { p2 = p;  i2 = e; }
        }
        float q1 = p1 / Z, q2 = p2 / Z;
        float denom = q1 + q2 + 1e-9f;
        float w1 = q1 / denom, w2 = q2 / denom;

        out_idx[(size_t)tok * 2 + 0] = (float)i1;
        out_idx[(size_t)tok * 2 + 1] = (float)i2;

        float* grow = out_gate + (size_t)tok * EE;
        for (int e = 0; e < EE; ++e)
            grow[e] = (e == i1) ? w1 : ((e == i2) ? w2 : 0.f);
    }
}

extern "C" void kernel_launch(void* const* d_in, const int* in_sizes, int n_in,
                              void* d_out, int out_size, void* d_ws, size_t ws_size,
                              hipStream_t stream) {
    const float* hs    = (const float*)d_in[0];
    const float* noise = (const float*)d_in[1];
    const float* wg    = (const float*)d_in[2];
    const float* wn    = (const float*)d_in[3];

    const int Ntok = in_sizes[1] / EE;    // noise is [N][64]
    const int Hdim = in_sizes[2] / EE;    // w_gate is [64][H]

    float* out_gate   = (float*)d_out;
    float* out_idx    = out_gate + (size_t)Ntok * EE;
    float* out_logits = out_idx  + (size_t)Ntok * 2;

    unsigned short* bp = (unsigned short*)d_ws;   // needs (H/32)*8*3*512*2 = 3 MB

    // pack W into MFMA B-fragment layout (3 bf16 terms)
    int pairs = (Hdim / 32) * 8;
    hipLaunchKernelGGL(pack_b, dim3(pairs / 4), dim3(256), 0, stream, wg, wn, bp, Hdim);

    hipLaunchKernelGGL(router_mfma, dim3(Ntok / BM), dim3(512), 0, stream,
                       hs, noise, bp, out_gate, out_idx, out_logits, Ntok, Hdim);
}